// Round 1
// baseline (469.213 us; speedup 1.0000x reference)
//
#include <hip/hip_runtime.h>
#include <hip/hip_bf16.h>

typedef unsigned short u16;
typedef __bf16 bf16x8 __attribute__((ext_vector_type(8)));
typedef float f32x4 __attribute__((ext_vector_type(4)));

#define S_LEN 2048
#define HID 2048
#define NH 32
#define NKV 8
#define HD 64

__device__ inline u16 f2bf(float x) {
    unsigned int u = __float_as_uint(x);
    unsigned int r = (u + 0x7fffu + ((u >> 16) & 1u)) >> 16;
    return (u16)r;
}
__device__ inline float bf2f(u16 u) {
    return __uint_as_float(((unsigned int)u) << 16);
}

// ---------------- fp32 -> bf16 convert ----------------
__global__ void cvt_f32_bf16(const float* __restrict__ in, u16* __restrict__ outp, int n4) {
    int i = blockIdx.x * blockDim.x + threadIdx.x;
    if (i < n4) {
        float4 v = ((const float4*)in)[i];
        ushort4 o;
        o.x = f2bf(v.x); o.y = f2bf(v.y); o.z = f2bf(v.z); o.w = f2bf(v.w);
        ((ushort4*)outp)[i] = o;
    }
}

// ---------------- GEMM: C[M,N] = A[M,K] * B[N,K]^T (both bf16 row-major) ----------------
// mode 0: store bf16 row-major (ldc)
// mode 1: store fp32 row-major (ldc)
// mode 2: store bf16 transposed: C[col*ldc + row]
__global__ __launch_bounds__(256) void gemm_bt(const u16* __restrict__ A,
                                               const u16* __restrict__ B,
                                               void* __restrict__ Cv,
                                               int K_, int mode, int ldc) {
    __shared__ u16 As[128][40];   // +8 pad: row stride 80B, 16B aligned, 2-way-max banks
    __shared__ u16 Bs[128][40];
    const int t = threadIdx.x;
    const int bm = blockIdx.x, bn = blockIdx.y;
    const int lane = t & 63, w = t >> 6;
    const int wr = (w >> 1) * 64, wc = (w & 1) * 64;
    const int g = lane >> 4, r16 = lane & 15;
    f32x4 acc[4][4] = {};
    const int row_s = t >> 2, half = t & 3;
    const size_t Abase = (size_t)(bm * 128 + row_s) * K_ + half * 8;
    const size_t Bbase = (size_t)(bn * 128 + row_s) * K_ + half * 8;

    for (int kt = 0; kt < K_; kt += 32) {
        int4 a0 = *(const int4*)(A + Abase + kt);
        int4 a1 = *(const int4*)(A + Abase + (size_t)64 * K_ + kt);
        int4 b0 = *(const int4*)(B + Bbase + kt);
        int4 b1 = *(const int4*)(B + Bbase + (size_t)64 * K_ + kt);
        __syncthreads();
        *(int4*)(&As[row_s][half * 8]) = a0;
        *(int4*)(&As[row_s + 64][half * 8]) = a1;
        *(int4*)(&Bs[row_s][half * 8]) = b0;
        *(int4*)(&Bs[row_s + 64][half * 8]) = b1;
        __syncthreads();
        bf16x8 af[4], bfr[4];
#pragma unroll
        for (int i = 0; i < 4; i++) af[i] = *(const bf16x8*)(&As[wr + i * 16 + r16][g * 8]);
#pragma unroll
        for (int j = 0; j < 4; j++) bfr[j] = *(const bf16x8*)(&Bs[wc + j * 16 + r16][g * 8]);
#pragma unroll
        for (int i = 0; i < 4; i++)
#pragma unroll
            for (int j = 0; j < 4; j++)
                acc[i][j] = __builtin_amdgcn_mfma_f32_16x16x32_bf16(af[i], bfr[j], acc[i][j], 0, 0, 0);
    }

#pragma unroll
    for (int i = 0; i < 4; i++)
#pragma unroll
        for (int j = 0; j < 4; j++)
#pragma unroll
            for (int r = 0; r < 4; r++) {
                int row = bm * 128 + wr + i * 16 + g * 4 + r;
                int col = bn * 128 + wc + j * 16 + r16;
                float v = acc[i][j][r];
                if (mode == 0)      ((u16*)Cv)[(size_t)row * ldc + col] = f2bf(v);
                else if (mode == 1) ((float*)Cv)[(size_t)row * ldc + col] = v;
                else                ((u16*)Cv)[(size_t)col * ldc + row] = f2bf(v);
            }
}

// ---------------- RoPE (in-place on bf16 q,k buffers) ----------------
__global__ void rope_kernel(u16* __restrict__ qb, u16* __restrict__ kb,
                            const float* __restrict__ cosp, const float* __restrict__ sinp) {
    int s = blockIdx.x;
    for (int it = threadIdx.x; it < (NH + NKV) * 32; it += blockDim.x) {
        int head = it >> 5, i = it & 31;
        u16* base = (head < NH) ? qb + (size_t)s * (NH * HD) + head * HD
                                : kb + (size_t)s * (NKV * HD) + (head - NH) * HD;
        float x1 = bf2f(base[i]), x2 = bf2f(base[i + 32]);
        float c1 = cosp[s * HD + i], s1 = sinp[s * HD + i];
        float c2 = cosp[s * HD + i + 32], s2 = sinp[s * HD + i + 32];
        base[i] = f2bf(x1 * c1 - x2 * s1);
        base[i + 32] = f2bf(x2 * c2 + x1 * s2);
    }
}

// ---------------- Flash attention (causal, GQA) ----------------
// q: [S, NH*HD] bf16 (rope'd), k: [S, NKV*HD] bf16 (rope'd), vT: [NKV*HD, S] bf16
// attn out: [S, NH*HD] bf16
__global__ __launch_bounds__(256) void attn_kernel(const u16* __restrict__ q,
                                                   const u16* __restrict__ k,
                                                   const u16* __restrict__ vT,
                                                   u16* __restrict__ attn) {
    __shared__ u16 P[4][16][72];  // per-wave P tile, padded rows (144B stride)
    const int qb = blockIdx.x, h = blockIdx.y;
    const int t = threadIdx.x, w = t >> 6, lane = t & 63;
    const int g = lane >> 4, r16 = lane & 15;
    const int kvh = h >> 2;
    const int qrow0 = qb * 64 + w * 16;

    bf16x8 qf[2];
#pragma unroll
    for (int d = 0; d < 2; d++)
        qf[d] = *(const bf16x8*)(q + (size_t)(qrow0 + r16) * (NH * HD) + h * HD + d * 32 + g * 8);

    float m_run[4], l_run[4];
    f32x4 o[4] = {};
#pragma unroll
    for (int r = 0; r < 4; r++) { m_run[r] = -1e30f; l_run[r] = 0.f; }

    const int kv_stop = qb * 64 + 64;
    for (int kv = 0; kv < kv_stop; kv += 64) {
        f32x4 sacc[4] = {};
#pragma unroll
        for (int sub = 0; sub < 4; sub++)
#pragma unroll
            for (int d = 0; d < 2; d++) {
                bf16x8 kf = *(const bf16x8*)(k + (size_t)(kv + sub * 16 + r16) * (NKV * HD) + kvh * HD + d * 32 + g * 8);
                sacc[sub] = __builtin_amdgcn_mfma_f32_16x16x32_bf16(qf[d], kf, sacc[sub], 0, 0, 0);
            }
        // scale + causal mask + per-row tile max
        float mt[4] = {-1e30f, -1e30f, -1e30f, -1e30f};
#pragma unroll
        for (int sub = 0; sub < 4; sub++)
#pragma unroll
            for (int r = 0; r < 4; r++) {
                float sv = sacc[sub][r] * 0.125f;
                int col = kv + sub * 16 + r16;
                int row = qrow0 + g * 4 + r;
                if (col > row) sv = -1e30f;
                sacc[sub][r] = sv;
                mt[r] = fmaxf(mt[r], sv);
            }
#pragma unroll
        for (int r = 0; r < 4; r++) {
            mt[r] = fmaxf(mt[r], __shfl_xor(mt[r], 1));
            mt[r] = fmaxf(mt[r], __shfl_xor(mt[r], 2));
            mt[r] = fmaxf(mt[r], __shfl_xor(mt[r], 4));
            mt[r] = fmaxf(mt[r], __shfl_xor(mt[r], 8));
        }
        float alpha[4], ps[4];
#pragma unroll
        for (int r = 0; r < 4; r++) {
            float mn = fmaxf(m_run[r], mt[r]);
            alpha[r] = __expf(m_run[r] - mn);
            m_run[r] = mn;
            ps[r] = 0.f;
        }
#pragma unroll
        for (int sub = 0; sub < 4; sub++)
#pragma unroll
            for (int r = 0; r < 4; r++) {
                float p = __expf(sacc[sub][r] - m_run[r]);
                sacc[sub][r] = p;
                ps[r] += p;
            }
#pragma unroll
        for (int r = 0; r < 4; r++) {
            ps[r] += __shfl_xor(ps[r], 1);
            ps[r] += __shfl_xor(ps[r], 2);
            ps[r] += __shfl_xor(ps[r], 4);
            ps[r] += __shfl_xor(ps[r], 8);
            l_run[r] = l_run[r] * alpha[r] + ps[r];
        }
#pragma unroll
        for (int dblk = 0; dblk < 4; dblk++)
#pragma unroll
            for (int r = 0; r < 4; r++) o[dblk][r] *= alpha[r];
        // P (C-layout) -> LDS -> A-fragment layout
#pragma unroll
        for (int sub = 0; sub < 4; sub++)
#pragma unroll
            for (int r = 0; r < 4; r++)
                P[w][g * 4 + r][sub * 16 + r16] = f2bf(sacc[sub][r]);
        __syncthreads();
#pragma unroll
        for (int khalf = 0; khalf < 2; khalf++) {
            bf16x8 pf = *(const bf16x8*)(&P[w][r16][khalf * 32 + g * 8]);
#pragma unroll
            for (int dblk = 0; dblk < 4; dblk++) {
                bf16x8 vf = *(const bf16x8*)(vT + (size_t)(kvh * HD + dblk * 16 + r16) * S_LEN + kv + khalf * 32 + g * 8);
                o[dblk] = __builtin_amdgcn_mfma_f32_16x16x32_bf16(pf, vf, o[dblk], 0, 0, 0);
            }
        }
        __syncthreads();
    }
#pragma unroll
    for (int dblk = 0; dblk < 4; dblk++)
#pragma unroll
        for (int r = 0; r < 4; r++) {
            float val = o[dblk][r] / l_run[r];
            attn[(size_t)(qrow0 + g * 4 + r) * (NH * HD) + h * HD + dblk * 16 + r16] = f2bf(val);
        }
}

extern "C" void kernel_launch(void* const* d_in, const int* in_sizes, int n_in,
                              void* d_out, int out_size, void* d_ws, size_t ws_size,
                              hipStream_t stream) {
    const float* hidden = (const float*)d_in[0];
    const float* Wq = (const float*)d_in[1];
    const float* Wk = (const float*)d_in[2];
    const float* Wv = (const float*)d_in[3];
    const float* Wo = (const float*)d_in[4];
    const float* cosp = (const float*)d_in[5];
    const float* sinp = (const float*)d_in[6];
    float* out = (float*)d_out;

    char* ws = (char*)d_ws;
    u16* hb   = (u16*)(ws);                        // 8 MB  [2048,2048]
    u16* wqb  = (u16*)(ws + ((size_t)8 << 20));    // 8 MB  [2048,2048]
    u16* wkb  = (u16*)(ws + ((size_t)16 << 20));   // 2 MB  [512,2048]
    u16* wvb  = (u16*)(ws + ((size_t)18 << 20));   // 2 MB  [512,2048]
    u16* wob  = (u16*)(ws + ((size_t)20 << 20));   // 8 MB  [2048,2048]
    u16* qbuf = (u16*)(ws + ((size_t)28 << 20));   // 8 MB  [2048,2048]
    u16* kbuf = (u16*)(ws + ((size_t)36 << 20));   // 2 MB  [2048,512]
    u16* vT   = (u16*)(ws + ((size_t)38 << 20));   // 2 MB  [512,2048]
    u16* attn = (u16*)(ws + ((size_t)40 << 20));   // 8 MB  [2048,2048]

    // fp32 -> bf16
    cvt_f32_bf16<<<4096, 256, 0, stream>>>(hidden, hb, 4194304 / 4);
    cvt_f32_bf16<<<4096, 256, 0, stream>>>(Wq, wqb, 4194304 / 4);
    cvt_f32_bf16<<<1024, 256, 0, stream>>>(Wk, wkb, 1048576 / 4);
    cvt_f32_bf16<<<1024, 256, 0, stream>>>(Wv, wvb, 1048576 / 4);
    cvt_f32_bf16<<<4096, 256, 0, stream>>>(Wo, wob, 4194304 / 4);

    // projections
    gemm_bt<<<dim3(16, 16), 256, 0, stream>>>(hb, wqb, qbuf, HID, 0, NH * HD);
    gemm_bt<<<dim3(16, 4), 256, 0, stream>>>(hb, wkb, kbuf, HID, 0, NKV * HD);
    gemm_bt<<<dim3(16, 4), 256, 0, stream>>>(hb, wvb, vT, HID, 2, S_LEN);

    // rope on q,k
    rope_kernel<<<S_LEN, 256, 0, stream>>>(qbuf, kbuf, cosp, sinp);

    // flash attention
    attn_kernel<<<dim3(S_LEN / 64, NH), 256, 0, stream>>>(qbuf, kbuf, vT, attn);

    // output projection -> fp32
    gemm_bt<<<dim3(16, 16), 256, 0, stream>>>(attn, wob, out, HID, 1, HID);

    (void)in_sizes; (void)n_in; (void)out_size; (void)ws_size;
}

// Round 2
// 286.537 us; speedup vs baseline: 1.6375x; 1.6375x over previous
//
#include <hip/hip_runtime.h>
#include <hip/hip_bf16.h>

typedef unsigned short u16;
typedef __bf16 bf16x8 __attribute__((ext_vector_type(8)));
typedef float f32x4 __attribute__((ext_vector_type(4)));

#define S_LEN 2048
#define HID 2048
#define NH 32
#define NKV 8
#define HD 64

__device__ inline u16 f2bf(float x) {
    unsigned int u = __float_as_uint(x);
    unsigned int r = (u + 0x7fffu + ((u >> 16) & 1u)) >> 16;
    return (u16)r;
}
__device__ inline float bf2f(u16 u) {
    return __uint_as_float(((unsigned int)u) << 16);
}

__device__ inline void gload_lds16(const u16* g, u16* l) {
    __builtin_amdgcn_global_load_lds((const __attribute__((address_space(1))) unsigned int*)g,
                                     (__attribute__((address_space(3))) unsigned int*)l, 16, 0, 0);
}

// ---------------- fp32 -> bf16 convert ----------------
__global__ void cvt_f32_bf16(const float* __restrict__ in, u16* __restrict__ outp, int n4) {
    int i = blockIdx.x * blockDim.x + threadIdx.x;
    if (i < n4) {
        float4 v = ((const float4*)in)[i];
        ushort4 o;
        o.x = f2bf(v.x); o.y = f2bf(v.y); o.z = f2bf(v.z); o.w = f2bf(v.w);
        ((ushort4*)outp)[i] = o;
    }
}

// ---------------- GEMM: C[M,N] = A[M,K] * B[N,K]^T (both bf16 row-major) ----------------
// m97-style: linear LDS + global_load_lds width 16, 128x128 tile, BK=32.
// mode 1: store fp32 row-major (ldc)
// mode 3: fused QKV epilogue: Cv=qbuf base; col<2048 -> qbuf, <2560 -> kbuf, else vT transposed
__global__ __launch_bounds__(256) void gemm_bt(const u16* __restrict__ A,
                                               const u16* __restrict__ B,
                                               void* __restrict__ Cv,
                                               int K_, int mode, int ldc) {
    __shared__ u16 As[128 * 32];
    __shared__ u16 Bs[128 * 32];
    const int t = threadIdx.x;
    const int bm = blockIdx.x, bn = blockIdx.y;
    const int lane = t & 63, w = t >> 6;
    const int wr = (w >> 1) * 64, wc = (w & 1) * 64;
    const int g = lane >> 4, r16 = lane & 15;
    f32x4 acc[4][4] = {};

    // staging: wave w covers tile rows [w*32, w*32+32), 2 instrs of 16 rows each
    const int srow = w * 32 + (lane >> 2);
    const int scol = (lane & 3) * 8;
    const u16* Ap = A + (size_t)(bm * 128 + srow) * K_ + scol;
    const u16* Bp = B + (size_t)(bn * 128 + srow) * K_ + scol;
    u16* AsW = &As[w * 1024];   // wave-uniform dest; HW adds lane*16B
    u16* BsW = &Bs[w * 1024];

    for (int kt = 0; kt < K_; kt += 32) {
        __syncthreads();   // prev tile's reads done before overwrite
        gload_lds16(Ap + kt, AsW);
        gload_lds16(Ap + kt + (size_t)16 * K_, AsW + 512);
        gload_lds16(Bp + kt, BsW);
        gload_lds16(Bp + kt + (size_t)16 * K_, BsW + 512);
        __syncthreads();   // drains vmcnt -> staged data visible to all waves
        bf16x8 af[4], bfr[4];
#pragma unroll
        for (int i = 0; i < 4; i++) af[i] = *(const bf16x8*)(&As[(wr + i * 16 + r16) * 32 + g * 8]);
#pragma unroll
        for (int j = 0; j < 4; j++) bfr[j] = *(const bf16x8*)(&Bs[(wc + j * 16 + r16) * 32 + g * 8]);
#pragma unroll
        for (int i = 0; i < 4; i++)
#pragma unroll
            for (int j = 0; j < 4; j++)
                acc[i][j] = __builtin_amdgcn_mfma_f32_16x16x32_bf16(af[i], bfr[j], acc[i][j], 0, 0, 0);
    }

    u16* qb_ = (u16*)Cv;
    u16* kb_ = qb_ + (size_t)2048 * 2048;
    u16* vt_ = kb_ + (size_t)512 * 2048;
#pragma unroll
    for (int i = 0; i < 4; i++)
#pragma unroll
        for (int j = 0; j < 4; j++)
#pragma unroll
            for (int r = 0; r < 4; r++) {
                int row = bm * 128 + wr + i * 16 + g * 4 + r;
                int col = bn * 128 + wc + j * 16 + r16;
                float v = acc[i][j][r];
                if (mode == 1) {
                    ((float*)Cv)[(size_t)row * ldc + col] = v;
                } else {  // mode 3 fused QKV
                    if (col < 2048)      qb_[(size_t)row * 2048 + col] = f2bf(v);
                    else if (col < 2560) kb_[(size_t)row * 512 + (col - 2048)] = f2bf(v);
                    else                 vt_[(size_t)(col - 2560) * 2048 + row] = f2bf(v);
                }
            }
}

// ---------------- RoPE (in-place; q additionally pre-scaled by 0.125*log2e) ----------------
__global__ void rope_kernel(u16* __restrict__ qb, u16* __restrict__ kb,
                            const float* __restrict__ cosp, const float* __restrict__ sinp) {
    const float QSCL = 0.125f * 1.44269504f;
    int s = blockIdx.x;
    for (int it = threadIdx.x; it < (NH + NKV) * 32; it += blockDim.x) {
        int head = it >> 5, i = it & 31;
        bool isq = head < NH;
        u16* base = isq ? qb + (size_t)s * (NH * HD) + head * HD
                        : kb + (size_t)s * (NKV * HD) + (head - NH) * HD;
        float scl = isq ? QSCL : 1.0f;
        float x1 = bf2f(base[i]), x2 = bf2f(base[i + 32]);
        float c1 = cosp[s * HD + i], s1 = sinp[s * HD + i];
        float c2 = cosp[s * HD + i + 32], s2 = sinp[s * HD + i + 32];
        base[i] = f2bf((x1 * c1 - x2 * s1) * scl);
        base[i + 32] = f2bf((x2 * c2 + x1 * s2) * scl);
    }
}

// ---------------- Flash attention (causal, GQA), barrier-free ----------------
// q: [S, NH*HD] bf16 (rope'd, pre-scaled), k: [S, NKV*HD], vT: [NKV*HD, S]
__global__ __launch_bounds__(256) void attn_kernel(const u16* __restrict__ q,
                                                   const u16* __restrict__ k,
                                                   const u16* __restrict__ vT,
                                                   u16* __restrict__ attn) {
    __shared__ u16 P[4][16][72];  // per-wave P tile; no cross-wave sharing -> no barriers
    const int bid = blockIdx.x;
    const int h = bid & 31, qb = bid >> 5;   // spreads qb across CUs (load balance)
    const int t = threadIdx.x, w = t >> 6, lane = t & 63;
    const int g = lane >> 4, r16 = lane & 15;
    const int kvh = h >> 2;
    const int qrow0 = qb * 64 + w * 16;
    const int qb64 = qb * 64;

    bf16x8 qf[2];
#pragma unroll
    for (int d = 0; d < 2; d++)
        qf[d] = *(const bf16x8*)(q + (size_t)(qrow0 + r16) * (NH * HD) + h * HD + d * 32 + g * 8);

    float m_run[4], l_run[4];
    f32x4 o[4] = {};
#pragma unroll
    for (int r = 0; r < 4; r++) { m_run[r] = -1e30f; l_run[r] = 0.f; }

    for (int kv = 0; kv <= qb64; kv += 64) {
        const bool diag = (kv == qb64);
        f32x4 sacc[4] = {};
#pragma unroll
        for (int sub = 0; sub < 4; sub++)
#pragma unroll
            for (int d = 0; d < 2; d++) {
                bf16x8 kf = *(const bf16x8*)(k + (size_t)(kv + sub * 16 + r16) * (NKV * HD) + kvh * HD + d * 32 + g * 8);
                sacc[sub] = __builtin_amdgcn_mfma_f32_16x16x32_bf16(qf[d], kf, sacc[sub], 0, 0, 0);
            }
        if (diag) {
#pragma unroll
            for (int sub = 0; sub < 4; sub++)
#pragma unroll
                for (int r = 0; r < 4; r++) {
                    int col = kv + sub * 16 + r16;
                    int row = qrow0 + g * 4 + r;
                    if (col > row) sacc[sub][r] = -1e30f;
                }
        }
        float mt[4];
#pragma unroll
        for (int r = 0; r < 4; r++)
            mt[r] = fmaxf(fmaxf(sacc[0][r], sacc[1][r]), fmaxf(sacc[2][r], sacc[3][r]));
#pragma unroll
        for (int r = 0; r < 4; r++) {
            mt[r] = fmaxf(mt[r], __shfl_xor(mt[r], 1));
            mt[r] = fmaxf(mt[r], __shfl_xor(mt[r], 2));
            mt[r] = fmaxf(mt[r], __shfl_xor(mt[r], 4));
            mt[r] = fmaxf(mt[r], __shfl_xor(mt[r], 8));
        }
        float alpha[4], ps[4];
#pragma unroll
        for (int r = 0; r < 4; r++) {
            float mn = fmaxf(m_run[r], mt[r]);
            alpha[r] = exp2f(m_run[r] - mn);
            m_run[r] = mn;
            ps[r] = 0.f;
        }
#pragma unroll
        for (int sub = 0; sub < 4; sub++)
#pragma unroll
            for (int r = 0; r < 4; r++) {
                float p = exp2f(sacc[sub][r] - m_run[r]);
                sacc[sub][r] = p;
                ps[r] += p;
            }
#pragma unroll
        for (int r = 0; r < 4; r++) {
            ps[r] += __shfl_xor(ps[r], 1);
            ps[r] += __shfl_xor(ps[r], 2);
            ps[r] += __shfl_xor(ps[r], 4);
            ps[r] += __shfl_xor(ps[r], 8);
            l_run[r] = l_run[r] * alpha[r] + ps[r];
        }
#pragma unroll
        for (int dblk = 0; dblk < 4; dblk++)
#pragma unroll
            for (int r = 0; r < 4; r++) o[dblk][r] *= alpha[r];
        // P (C-layout) -> LDS -> A-fragment layout. Same-wave DS ops are ordered;
        // compiler inserts lgkmcnt for the read data. No block barrier needed.
#pragma unroll
        for (int sub = 0; sub < 4; sub++)
#pragma unroll
            for (int r = 0; r < 4; r++)
                P[w][g * 4 + r][sub * 16 + r16] = f2bf(sacc[sub][r]);
#pragma unroll
        for (int khalf = 0; khalf < 2; khalf++) {
            bf16x8 pf = *(const bf16x8*)(&P[w][r16][khalf * 32 + g * 8]);
#pragma unroll
            for (int dblk = 0; dblk < 4; dblk++) {
                bf16x8 vf = *(const bf16x8*)(vT + (size_t)(kvh * HD + dblk * 16 + r16) * S_LEN + kv + khalf * 32 + g * 8);
                o[dblk] = __builtin_amdgcn_mfma_f32_16x16x32_bf16(pf, vf, o[dblk], 0, 0, 0);
            }
        }
    }
#pragma unroll
    for (int dblk = 0; dblk < 4; dblk++)
#pragma unroll
        for (int r = 0; r < 4; r++) {
            float val = o[dblk][r] / l_run[r];
            attn[(size_t)(qrow0 + g * 4 + r) * (NH * HD) + h * HD + dblk * 16 + r16] = f2bf(val);
        }
}

extern "C" void kernel_launch(void* const* d_in, const int* in_sizes, int n_in,
                              void* d_out, int out_size, void* d_ws, size_t ws_size,
                              hipStream_t stream) {
    const float* hidden = (const float*)d_in[0];
    const float* Wq = (const float*)d_in[1];
    const float* Wk = (const float*)d_in[2];
    const float* Wv = (const float*)d_in[3];
    const float* Wo = (const float*)d_in[4];
    const float* cosp = (const float*)d_in[5];
    const float* sinp = (const float*)d_in[6];
    float* out = (float*)d_out;

    char* ws = (char*)d_ws;
    u16* hb   = (u16*)(ws);                        // 8 MB  [2048,2048]
    u16* wqkv = (u16*)(ws + ((size_t)8 << 20));    // 12 MB [3072,2048] (Wq;Wk;Wv)
    u16* wob  = (u16*)(ws + ((size_t)20 << 20));   // 8 MB  [2048,2048]
    u16* qbuf = (u16*)(ws + ((size_t)28 << 20));   // 8 MB  [2048,2048]  (kbuf, vT follow contiguously)
    u16* kbuf = qbuf + (size_t)2048 * 2048;        // 2 MB  [2048,512]
    u16* vT   = kbuf + (size_t)512 * 2048;         // 2 MB  [512,2048]
    u16* attn = (u16*)(ws + ((size_t)40 << 20));   // 8 MB  [2048,2048]

    // fp32 -> bf16 (weights concatenated into wqkv)
    cvt_f32_bf16<<<4096, 256, 0, stream>>>(hidden, hb, 4194304 / 4);
    cvt_f32_bf16<<<4096, 256, 0, stream>>>(Wq, wqkv, 4194304 / 4);
    cvt_f32_bf16<<<1024, 256, 0, stream>>>(Wk, wqkv + (size_t)2048 * 2048, 1048576 / 4);
    cvt_f32_bf16<<<1024, 256, 0, stream>>>(Wv, wqkv + (size_t)2560 * 2048, 1048576 / 4);
    cvt_f32_bf16<<<4096, 256, 0, stream>>>(Wo, wob, 4194304 / 4);

    // fused QKV projection: [2048,2048] x [3072,2048]^T
    gemm_bt<<<dim3(16, 24), 256, 0, stream>>>(hb, wqkv, qbuf, HID, 3, 0);

    // rope on q (pre-scaled), k
    rope_kernel<<<S_LEN, 256, 0, stream>>>(qbuf, kbuf, cosp, sinp);

    // flash attention (1D grid, load-balanced)
    attn_kernel<<<S_LEN / 64 * NH, 256, 0, stream>>>(qbuf, kbuf, vT, attn);

    // output projection -> fp32
    gemm_bt<<<dim3(16, 16), 256, 0, stream>>>(attn, wob, out, HID, 1, HID);

    (void)in_sizes; (void)n_in; (void)out_size; (void)ws_size;
}

// Round 3
// 235.851 us; speedup vs baseline: 1.9894x; 1.2149x over previous
//
#include <hip/hip_runtime.h>
#include <hip/hip_bf16.h>

typedef unsigned short u16;
typedef __bf16 bf16x8 __attribute__((ext_vector_type(8)));
typedef float f32x4 __attribute__((ext_vector_type(4)));

#define S_LEN 2048
#define HID 2048
#define NH 32
#define NKV 8
#define HD 64

__device__ inline u16 f2bf(float x) {
    unsigned int u = __float_as_uint(x);
    unsigned int r = (u + 0x7fffu + ((u >> 16) & 1u)) >> 16;
    return (u16)r;
}
__device__ inline float bf2f(u16 u) {
    return __uint_as_float(((unsigned int)u) << 16);
}

__device__ inline void gload_lds16(const u16* g, u16* l) {
    __builtin_amdgcn_global_load_lds((const __attribute__((address_space(1))) unsigned int*)g,
                                     (__attribute__((address_space(3))) unsigned int*)l, 16, 0, 0);
}

// ---------------- fp32 -> bf16 convert ----------------
__global__ void cvt_f32_bf16(const float* __restrict__ in, u16* __restrict__ outp, int n4) {
    int i = blockIdx.x * blockDim.x + threadIdx.x;
    if (i < n4) {
        float4 v = ((const float4*)in)[i];
        ushort4 o;
        o.x = f2bf(v.x); o.y = f2bf(v.y); o.z = f2bf(v.z); o.w = f2bf(v.w);
        ((ushort4*)outp)[i] = o;
    }
}

// ---------------- GEMM: C[M,N] = A[M,K] * B[N,K]^T (both bf16 row-major) ----------------
// m97-style: linear LDS + global_load_lds width 16, 128x128 tile, BK=32.
// mode 1: store fp32 row-major (ldc)
// mode 3: fused QKV epilogue: Cv=qbuf base; col<2048 -> qbuf, <2560 -> kbuf, else vT transposed
__global__ __launch_bounds__(256) void gemm_bt(const u16* __restrict__ A,
                                               const u16* __restrict__ B,
                                               void* __restrict__ Cv,
                                               int K_, int mode, int ldc) {
    __shared__ u16 As[128 * 32];
    __shared__ u16 Bs[128 * 32];
    const int t = threadIdx.x;
    const int bm = blockIdx.x, bn = blockIdx.y;
    const int lane = t & 63, w = t >> 6;
    const int wr = (w >> 1) * 64, wc = (w & 1) * 64;
    const int g = lane >> 4, r16 = lane & 15;
    f32x4 acc[4][4] = {};

    const int srow = w * 32 + (lane >> 2);
    const int scol = (lane & 3) * 8;
    const u16* Ap = A + (size_t)(bm * 128 + srow) * K_ + scol;
    const u16* Bp = B + (size_t)(bn * 128 + srow) * K_ + scol;
    u16* AsW = &As[w * 1024];
    u16* BsW = &Bs[w * 1024];

    for (int kt = 0; kt < K_; kt += 32) {
        __syncthreads();
        gload_lds16(Ap + kt, AsW);
        gload_lds16(Ap + kt + (size_t)16 * K_, AsW + 512);
        gload_lds16(Bp + kt, BsW);
        gload_lds16(Bp + kt + (size_t)16 * K_, BsW + 512);
        __syncthreads();
        bf16x8 af[4], bfr[4];
#pragma unroll
        for (int i = 0; i < 4; i++) af[i] = *(const bf16x8*)(&As[(wr + i * 16 + r16) * 32 + g * 8]);
#pragma unroll
        for (int j = 0; j < 4; j++) bfr[j] = *(const bf16x8*)(&Bs[(wc + j * 16 + r16) * 32 + g * 8]);
#pragma unroll
        for (int i = 0; i < 4; i++)
#pragma unroll
            for (int j = 0; j < 4; j++)
                acc[i][j] = __builtin_amdgcn_mfma_f32_16x16x32_bf16(af[i], bfr[j], acc[i][j], 0, 0, 0);
    }

    u16* qb_ = (u16*)Cv;
    u16* kb_ = qb_ + (size_t)2048 * 2048;
    u16* vt_ = kb_ + (size_t)512 * 2048;
#pragma unroll
    for (int i = 0; i < 4; i++)
#pragma unroll
        for (int j = 0; j < 4; j++)
#pragma unroll
            for (int r = 0; r < 4; r++) {
                int row = bm * 128 + wr + i * 16 + g * 4 + r;
                int col = bn * 128 + wc + j * 16 + r16;
                float v = acc[i][j][r];
                if (mode == 1) {
                    ((float*)Cv)[(size_t)row * ldc + col] = v;
                } else {
                    if (col < 2048)      qb_[(size_t)row * 2048 + col] = f2bf(v);
                    else if (col < 2560) kb_[(size_t)row * 512 + (col - 2048)] = f2bf(v);
                    else                 vt_[(size_t)(col - 2560) * 2048 + row] = f2bf(v);
                }
            }
}

// ---------------- RoPE (in-place; q additionally pre-scaled by 0.125*log2e) ----------------
__global__ void rope_kernel(u16* __restrict__ qb, u16* __restrict__ kb,
                            const float* __restrict__ cosp, const float* __restrict__ sinp) {
    const float QSCL = 0.125f * 1.44269504f;
    int s = blockIdx.x;
    for (int it = threadIdx.x; it < (NH + NKV) * 32; it += blockDim.x) {
        int head = it >> 5, i = it & 31;
        bool isq = head < NH;
        u16* base = isq ? qb + (size_t)s * (NH * HD) + head * HD
                        : kb + (size_t)s * (NKV * HD) + (head - NH) * HD;
        float scl = isq ? QSCL : 1.0f;
        float x1 = bf2f(base[i]), x2 = bf2f(base[i + 32]);
        float c1 = cosp[s * HD + i], s1 = sinp[s * HD + i];
        float c2 = cosp[s * HD + i + 32], s2 = sinp[s * HD + i + 32];
        base[i] = f2bf((x1 * c1 - x2 * s1) * scl);
        base[i + 32] = f2bf((x2 * c2 + x1 * s2) * scl);
    }
}

// ---------------- Flash attention (causal, GQA) ----------------
// 1 wave per block, 32 q-rows per wave (two 16-row fragments sharing K/V loads).
// q: [S, NH*HD] bf16 (rope'd, pre-scaled), k: [S, NKV*HD], vT: [NKV*HD, S]
__global__ __launch_bounds__(64) void attn_kernel(const u16* __restrict__ q,
                                                  const u16* __restrict__ k,
                                                  const u16* __restrict__ vT,
                                                  u16* __restrict__ attn) {
    __shared__ u16 P[2][16][72];  // per-fragment P tile (single wave -> no barriers)
    const int bid = blockIdx.x;
    const int h = bid & 31, qblk = bid >> 5;   // qblk 0..63, 32 rows each
    const int lane = threadIdx.x & 63;
    const int g = lane >> 4, r16 = lane & 15;
    const int kvh = h >> 2;
    const int qrow0 = qblk * 32;

    bf16x8 qf[2][2];
#pragma unroll
    for (int fi = 0; fi < 2; fi++)
#pragma unroll
        for (int d = 0; d < 2; d++)
            qf[fi][d] = *(const bf16x8*)(q + (size_t)(qrow0 + fi * 16 + r16) * (NH * HD) + h * HD + d * 32 + g * 8);

    float m_run[2][4], l_run[2][4];
    f32x4 o[2][4] = {};
#pragma unroll
    for (int fi = 0; fi < 2; fi++)
#pragma unroll
        for (int r = 0; r < 4; r++) { m_run[fi][r] = -1e30f; l_run[fi][r] = 0.f; }

    const int last = (qrow0 >> 6) << 6;   // last KV tile start
    for (int kv = 0; kv <= last; kv += 64) {
        const bool diag = (kv == last);
        // ---- K fragment loads (shared by both q-fragments) ----
        bf16x8 kf[4][2];
#pragma unroll
        for (int sub = 0; sub < 4; sub++)
#pragma unroll
            for (int d = 0; d < 2; d++)
                kf[sub][d] = *(const bf16x8*)(k + (size_t)(kv + sub * 16 + r16) * (NKV * HD) + kvh * HD + d * 32 + g * 8);
        // ---- QK^T: 16 MFMA, two independent chains ----
        f32x4 sacc[2][4] = {};
#pragma unroll
        for (int sub = 0; sub < 4; sub++)
#pragma unroll
            for (int fi = 0; fi < 2; fi++)
#pragma unroll
                for (int d = 0; d < 2; d++)
                    sacc[fi][sub] = __builtin_amdgcn_mfma_f32_16x16x32_bf16(qf[fi][d], kf[sub][d], sacc[fi][sub], 0, 0, 0);
        // ---- V fragment loads issued early: latency hides under softmax ----
        bf16x8 vf[2][4];
#pragma unroll
        for (int khalf = 0; khalf < 2; khalf++)
#pragma unroll
            for (int dblk = 0; dblk < 4; dblk++)
                vf[khalf][dblk] = *(const bf16x8*)(vT + (size_t)(kvh * HD + dblk * 16 + r16) * S_LEN + kv + khalf * 32 + g * 8);
        // ---- softmax (per fragment, independent) ----
        if (diag) {
#pragma unroll
            for (int fi = 0; fi < 2; fi++)
#pragma unroll
                for (int sub = 0; sub < 4; sub++)
#pragma unroll
                    for (int r = 0; r < 4; r++) {
                        int col = kv + sub * 16 + r16;
                        int row = qrow0 + fi * 16 + g * 4 + r;
                        if (col > row) sacc[fi][sub][r] = -1e30f;
                    }
        }
#pragma unroll
        for (int fi = 0; fi < 2; fi++) {
            float mt[4];
#pragma unroll
            for (int r = 0; r < 4; r++)
                mt[r] = fmaxf(fmaxf(sacc[fi][0][r], sacc[fi][1][r]), fmaxf(sacc[fi][2][r], sacc[fi][3][r]));
#pragma unroll
            for (int r = 0; r < 4; r++) {
                mt[r] = fmaxf(mt[r], __shfl_xor(mt[r], 1));
                mt[r] = fmaxf(mt[r], __shfl_xor(mt[r], 2));
                mt[r] = fmaxf(mt[r], __shfl_xor(mt[r], 4));
                mt[r] = fmaxf(mt[r], __shfl_xor(mt[r], 8));
            }
            float alpha[4], ps[4];
#pragma unroll
            for (int r = 0; r < 4; r++) {
                float mn = fmaxf(m_run[fi][r], mt[r]);
                alpha[r] = exp2f(m_run[fi][r] - mn);
                m_run[fi][r] = mn;
                ps[r] = 0.f;
            }
#pragma unroll
            for (int sub = 0; sub < 4; sub++)
#pragma unroll
                for (int r = 0; r < 4; r++) {
                    float p = exp2f(sacc[fi][sub][r] - m_run[fi][r]);
                    sacc[fi][sub][r] = p;
                    ps[r] += p;
                }
#pragma unroll
            for (int r = 0; r < 4; r++) {
                ps[r] += __shfl_xor(ps[r], 1);
                ps[r] += __shfl_xor(ps[r], 2);
                ps[r] += __shfl_xor(ps[r], 4);
                ps[r] += __shfl_xor(ps[r], 8);
                l_run[fi][r] = l_run[fi][r] * alpha[r] + ps[r];
            }
#pragma unroll
            for (int dblk = 0; dblk < 4; dblk++)
#pragma unroll
                for (int r = 0; r < 4; r++) o[fi][dblk][r] *= alpha[r];
            // P (C-layout) -> LDS (per-fragment buffer)
#pragma unroll
            for (int sub = 0; sub < 4; sub++)
#pragma unroll
                for (int r = 0; r < 4; r++)
                    P[fi][g * 4 + r][sub * 16 + r16] = f2bf(sacc[fi][sub][r]);
        }
        // ---- PV: 16 MFMA, two independent chains ----
#pragma unroll
        for (int fi = 0; fi < 2; fi++)
#pragma unroll
            for (int khalf = 0; khalf < 2; khalf++) {
                bf16x8 pf = *(const bf16x8*)(&P[fi][r16][khalf * 32 + g * 8]);
#pragma unroll
                for (int dblk = 0; dblk < 4; dblk++)
                    o[fi][dblk] = __builtin_amdgcn_mfma_f32_16x16x32_bf16(pf, vf[khalf][dblk], o[fi][dblk], 0, 0, 0);
            }
    }
#pragma unroll
    for (int fi = 0; fi < 2; fi++)
#pragma unroll
        for (int dblk = 0; dblk < 4; dblk++)
#pragma unroll
            for (int r = 0; r < 4; r++) {
                float val = o[fi][dblk][r] / l_run[fi][r];
                attn[(size_t)(qrow0 + fi * 16 + g * 4 + r) * (NH * HD) + h * HD + dblk * 16 + r16] = f2bf(val);
            }
}

extern "C" void kernel_launch(void* const* d_in, const int* in_sizes, int n_in,
                              void* d_out, int out_size, void* d_ws, size_t ws_size,
                              hipStream_t stream) {
    const float* hidden = (const float*)d_in[0];
    const float* Wq = (const float*)d_in[1];
    const float* Wk = (const float*)d_in[2];
    const float* Wv = (const float*)d_in[3];
    const float* Wo = (const float*)d_in[4];
    const float* cosp = (const float*)d_in[5];
    const float* sinp = (const float*)d_in[6];
    float* out = (float*)d_out;

    char* ws = (char*)d_ws;
    u16* hb   = (u16*)(ws);                        // 8 MB  [2048,2048]
    u16* wqkv = (u16*)(ws + ((size_t)8 << 20));    // 12 MB [3072,2048] (Wq;Wk;Wv)
    u16* wob  = (u16*)(ws + ((size_t)20 << 20));   // 8 MB  [2048,2048]
    u16* qbuf = (u16*)(ws + ((size_t)28 << 20));   // 8 MB  [2048,2048]  (kbuf, vT follow contiguously)
    u16* kbuf = qbuf + (size_t)2048 * 2048;        // 2 MB  [2048,512]
    u16* vT   = kbuf + (size_t)512 * 2048;         // 2 MB  [512,2048]
    u16* attn = (u16*)(ws + ((size_t)40 << 20));   // 8 MB  [2048,2048]

    cvt_f32_bf16<<<4096, 256, 0, stream>>>(hidden, hb, 4194304 / 4);
    cvt_f32_bf16<<<4096, 256, 0, stream>>>(Wq, wqkv, 4194304 / 4);
    cvt_f32_bf16<<<1024, 256, 0, stream>>>(Wk, wqkv + (size_t)2048 * 2048, 1048576 / 4);
    cvt_f32_bf16<<<1024, 256, 0, stream>>>(Wv, wqkv + (size_t)2560 * 2048, 1048576 / 4);
    cvt_f32_bf16<<<4096, 256, 0, stream>>>(Wo, wob, 4194304 / 4);

    gemm_bt<<<dim3(16, 24), 256, 0, stream>>>(hb, wqkv, qbuf, HID, 3, 0);

    rope_kernel<<<S_LEN, 256, 0, stream>>>(qbuf, kbuf, cosp, sinp);

    // flash attention: 1 wave/block, 32 q-rows/wave
    attn_kernel<<<S_LEN / 32 * NH, 64, 0, stream>>>(qbuf, kbuf, vT, attn);

    gemm_bt<<<dim3(16, 16), 256, 0, stream>>>(attn, wob, out, HID, 1, HID);

    (void)in_sizes; (void)n_in; (void)out_size; (void)ws_size;
}